// Round 1
// baseline (276.846 us; speedup 1.0000x reference)
//
#include <hip/hip_runtime.h>
#include <hip/hip_bf16.h>

#define N 4096
#define IND 256
#define OUTD 128
#define NEGV -9000000000000000.0f

// ---------------- Kernel A: wh = lstm_out @ W  (4096x256 @ 256x128) ----------------
__global__ __launch_bounds__(256) void wh_kernel(const float* __restrict__ x,
                                                 const float* __restrict__ W,
                                                 float* __restrict__ wh) {
    __shared__ float xs[16][IND];
    const int t = threadIdx.x;
    const int i0 = blockIdx.x * 16;
    // cooperative load: 16 rows x 256 floats = 1024 float4
    const float4* src = (const float4*)(x + (size_t)i0 * IND);
    float4* dst = (float4*)&xs[0][0];
    #pragma unroll
    for (int q = 0; q < 4; ++q) dst[t + q * 256] = src[t + q * 256];
    __syncthreads();
    const int c = t & 127;
    const int rh = t >> 7;  // 0..1 -> rows rh*8 .. rh*8+7
    float acc[8];
    #pragma unroll
    for (int r = 0; r < 8; ++r) acc[r] = 0.f;
    for (int k = 0; k < IND; ++k) {
        float w = W[k * OUTD + c];
        #pragma unroll
        for (int r = 0; r < 8; ++r) acc[r] = fmaf(xs[rh * 8 + r][k], w, acc[r]);
    }
    #pragma unroll
    for (int r = 0; r < 8; ++r)
        wh[(size_t)(i0 + rh * 8 + r) * OUTD + c] = acc[r];
}

// ---------------- Kernel A2: s_i = wh @ a_i, s_j = wh @ a_j ----------------
__global__ __launch_bounds__(128) void sij_kernel(const float* __restrict__ wh,
                                                  const float* __restrict__ a,
                                                  float* __restrict__ s_i,
                                                  float* __restrict__ s_j) {
    const int i = blockIdx.x;
    const int c = threadIdx.x;
    float v = wh[(size_t)i * OUTD + c];
    float p = v * a[c];              // a_i = a[0:128]
    float q = v * a[OUTD + 5 + c];   // a_j = a[133:261]
    #pragma unroll
    for (int off = 32; off >= 1; off >>= 1) {
        p += __shfl_down(p, off);
        q += __shfl_down(q, off);
    }
    __shared__ float tmp[4];
    if ((c & 63) == 0) { tmp[c >> 6] = p; tmp[2 + (c >> 6)] = q; }
    __syncthreads();
    if (c == 0) { s_i[i] = tmp[0] + tmp[1]; s_j[i] = tmp[2] + tmp[3]; }
}

// ---------------- Kernel B: fused scores + online softmax + PV ----------------
// Block: 256 threads, BI=8 rows, j-tiles of BJ=512 (8 tiles).
// Phase 1 mapping: r = t>>5 (8 rows), s = t&31, j = j0 + s + 32k (k=0..15).
// Phase 2 mapping: c = t&127 (col), jh = t>>7 (j-half) — each thread does all 8 rows.
#define BI 8
#define BJ 512
#define PSTR (BJ + 8)   // 520-float row stride: 16B-aligned rows, <=2-way bank alias

__global__ __launch_bounds__(256) void gat_fused(const float* __restrict__ edges,
                                                 const float* __restrict__ wh,
                                                 const float* __restrict__ s_iv,
                                                 const float* __restrict__ s_jv,
                                                 float* __restrict__ out,
                                                 const float* __restrict__ a) {
    __shared__ float P[BI][PSTR];
    __shared__ float fbuf[BI];
    __shared__ float lbuf[BI];
    const int t = threadIdx.x;
    const int i0 = blockIdx.x * BI;

    const int r = t >> 5;
    const int s = t & 31;
    const int i = i0 + r;
    const float ae0 = a[OUTD + 0], ae1 = a[OUTD + 1], ae2 = a[OUTD + 2],
                ae3 = a[OUTD + 3], ae4 = a[OUTD + 4];
    const float si = s_iv[i];
    float m = -1e30f;
    float l = 0.f;

    const int c = t & 127;
    const int jh = t >> 7;
    float acc[BI];
    #pragma unroll
    for (int q = 0; q < BI; ++q) acc[q] = 0.f;

    for (int tile = 0; tile < N / BJ; ++tile) {
        const int j0 = tile * BJ;
        // ---- phase 1: 16 scores per thread for row i ----
        float sc[16];
        float lmax = -1e30f;
        const float* eb = edges + ((size_t)i * N + (j0 + s)) * 5;
        #pragma unroll
        for (int k = 0; k < 16; ++k) {
            const float* e = eb + k * (32 * 5);
            float d = e[0] * ae0;
            d = fmaf(e[1], ae1, d);
            d = fmaf(e[2], ae2, d);
            d = fmaf(e[3], ae3, d);
            d = fmaf(e[4], ae4, d);
            const int j = j0 + s + k * 32;
            float v = si + d + s_jv[j];
            v = v > 0.f ? v : 0.2f * v;   // leaky relu BEFORE mask (matches ref)
            if (j == i) v = NEGV;         // diagonal mask
            sc[k] = v;
            lmax = fmaxf(lmax, v);
        }
        // row max over the 16 lanes... (32-lane group: offsets 16..1 stay in-group)
        #pragma unroll
        for (int off = 16; off >= 1; off >>= 1)
            lmax = fmaxf(lmax, __shfl_xor(lmax, off));
        const float newm = fmaxf(m, lmax);
        const float f = __expf(m - newm);
        m = newm;
        float lsum = 0.f;
        #pragma unroll
        for (int k = 0; k < 16; ++k) {
            float p = __expf(sc[k] - m);
            lsum += p;
            P[r][s + k * 32] = p;
        }
        #pragma unroll
        for (int off = 16; off >= 1; off >>= 1)
            lsum += __shfl_xor(lsum, off);
        l = fmaf(l, f, lsum);
        if (s == 0) fbuf[r] = f;
        __syncthreads();

        // ---- phase 2: PV over this tile's j-half ----
        {
            float fr[BI];
            #pragma unroll
            for (int q = 0; q < BI; ++q) fr[q] = fbuf[q];
            #pragma unroll
            for (int q = 0; q < BI; ++q) acc[q] *= fr[q];
            const int jb = jh * (BJ / 2);
            const float* whp = wh + (size_t)(j0 + jb) * OUTD + c;
            #pragma unroll 4
            for (int jj = 0; jj < BJ / 2; jj += 4) {
                float w0 = whp[(jj + 0) * OUTD];
                float w1 = whp[(jj + 1) * OUTD];
                float w2 = whp[(jj + 2) * OUTD];
                float w3 = whp[(jj + 3) * OUTD];
                #pragma unroll
                for (int q = 0; q < BI; ++q) {
                    float4 pv = *(const float4*)&P[q][jb + jj];
                    acc[q] = fmaf(pv.x, w0, acc[q]);
                    acc[q] = fmaf(pv.y, w1, acc[q]);
                    acc[q] = fmaf(pv.z, w2, acc[q]);
                    acc[q] = fmaf(pv.w, w3, acc[q]);
                }
            }
        }
        __syncthreads();
    }

    if (s == 0) lbuf[r] = l;
    __syncthreads();
    // cross-half reduce (reuse P as scratch), then scale by 1/l and store
    if (jh == 1) {
        #pragma unroll
        for (int q = 0; q < BI; ++q) P[q][c] = acc[q];
    }
    __syncthreads();
    if (jh == 0) {
        #pragma unroll
        for (int q = 0; q < BI; ++q) {
            float v = (acc[q] + P[q][c]) / lbuf[q];
            out[(size_t)(i0 + q) * OUTD + c] = v;
        }
    }
}

extern "C" void kernel_launch(void* const* d_in, const int* in_sizes, int n_in,
                              void* d_out, int out_size, void* d_ws, size_t ws_size,
                              hipStream_t stream) {
    // inputs: 0=ids(int, unused), 1=lstm_out, 2=edges_list, 3=W, 4=a, 5=first(unused)
    const float* lstm_out = (const float*)d_in[1];
    const float* edges    = (const float*)d_in[2];
    const float* W        = (const float*)d_in[3];
    const float* a        = (const float*)d_in[4];
    float* out = (float*)d_out;

    float* wh  = (float*)d_ws;                 // 4096*128 f32 = 2 MB
    float* s_i = wh + (size_t)N * OUTD;        // 4096 f32
    float* s_j = s_i + N;                      // 4096 f32

    wh_kernel<<<N / 16, 256, 0, stream>>>(lstm_out, W, wh);
    sij_kernel<<<N, 128, 0, stream>>>(wh, a, s_i, s_j);
    gat_fused<<<N / BI, 256, 0, stream>>>(edges, wh, s_i, s_j, out, a);
}

// Round 2
// 180.798 us; speedup vs baseline: 1.5312x; 1.5312x over previous
//
#include <hip/hip_runtime.h>
#include <hip/hip_bf16.h>

#define N 4096
#define IND 256
#define OUTD 128
#define NEGV -9000000000000000.0f

// ---------------- Kernel A: wh = lstm_out @ W  (4096x256 @ 256x128) ----------------
__global__ __launch_bounds__(256) void wh_kernel(const float* __restrict__ x,
                                                 const float* __restrict__ W,
                                                 float* __restrict__ wh) {
    __shared__ float xs[16][IND];
    const int t = threadIdx.x;
    const int i0 = blockIdx.x * 16;
    const float4* src = (const float4*)(x + (size_t)i0 * IND);
    float4* dst = (float4*)&xs[0][0];
    #pragma unroll
    for (int q = 0; q < 4; ++q) dst[t + q * 256] = src[t + q * 256];
    __syncthreads();
    const int c = t & 127;
    const int rh = t >> 7;
    float acc[8];
    #pragma unroll
    for (int r = 0; r < 8; ++r) acc[r] = 0.f;
    for (int k = 0; k < IND; ++k) {
        float w = W[k * OUTD + c];
        #pragma unroll
        for (int r = 0; r < 8; ++r) acc[r] = fmaf(xs[rh * 8 + r][k], w, acc[r]);
    }
    #pragma unroll
    for (int r = 0; r < 8; ++r)
        wh[(size_t)(i0 + rh * 8 + r) * OUTD + c] = acc[r];
}

// ---------------- Kernel A2: s_i = wh @ a_i, s_j = wh @ a_j ----------------
__global__ __launch_bounds__(128) void sij_kernel(const float* __restrict__ wh,
                                                  const float* __restrict__ a,
                                                  float* __restrict__ s_i,
                                                  float* __restrict__ s_j) {
    const int i = blockIdx.x;
    const int c = threadIdx.x;
    float v = wh[(size_t)i * OUTD + c];
    float p = v * a[c];              // a_i = a[0:128]
    float q = v * a[OUTD + 5 + c];   // a_j = a[133:261]
    #pragma unroll
    for (int off = 32; off >= 1; off >>= 1) {
        p += __shfl_down(p, off);
        q += __shfl_down(q, off);
    }
    __shared__ float tmp[4];
    if ((c & 63) == 0) { tmp[c >> 6] = p; tmp[2 + (c >> 6)] = q; }
    __syncthreads();
    if (c == 0) { s_i[i] = tmp[0] + tmp[1]; s_j[i] = tmp[2] + tmp[3]; }
}

// ---------------- Kernel B: fused scores + online softmax + PV ----------------
// 1024 threads = 4 quarters of 256. Quarter q owns j-chunk [q*1024, q*1024+1024),
// processed as 2 tiles of BJ=512. Grid = N/BI = 512 blocks -> 2 blocks/CU, 32 waves/CU.
// Phase 1 (per quarter): r1 = (t>>5)&7 (8 rows), s = t&31, 16 j per lane.
//   Raw scores -> P (register relief), row-max reduce, then exp in place.
// Phase 2 (per quarter): c2 = t&63 (cols 2c2, 2c2+1), jq = (t>>6)&3 (128-j slice).
//   P reads are wave-uniform (broadcast, conflict-free); wh read as float2.
// Final: cross-quarter softmax merge in LDS (red overlays P).
#define BI 8
#define BJ 512
#define NQ 4
#define TPQ 2              // tiles per quarter: N / (NQ*BJ)
#define PSTR 520           // row stride: 16B-aligned, phase-1 write alias only 2-way (free)

__global__ __launch_bounds__(1024, 8) void gat_fused(const float* __restrict__ edges,
                                                     const float* __restrict__ wh,
                                                     const float* __restrict__ s_iv,
                                                     const float* __restrict__ s_jv,
                                                     float* __restrict__ out,
                                                     const float* __restrict__ a) {
    __shared__ float P[NQ][BI][PSTR];   // 66.5 KB; also reused as red[16][BI][128]
    __shared__ float fbuf[NQ][BI];
    __shared__ float mbuf[NQ][BI];
    __shared__ float lbuf[NQ][BI];

    const int t = threadIdx.x;
    const int i0 = blockIdx.x * BI;
    const int q = t >> 8;            // quarter 0..3

    // phase-1 identity
    const int r1 = (t >> 5) & 7;
    const int s = t & 31;
    const int i = i0 + r1;

    // phase-2 identity
    const int c2 = t & 63;           // cols 2*c2, 2*c2+1
    const int jq = (t >> 6) & 3;     // 128-j slice within tile

    const float ae0 = a[OUTD + 0], ae1 = a[OUTD + 1], ae2 = a[OUTD + 2],
                ae3 = a[OUTD + 3], ae4 = a[OUTD + 4];
    const float si = s_iv[i];
    float m = -1e30f;
    float l = 0.f;
    float acc[BI][2];
    #pragma unroll
    for (int rr = 0; rr < BI; ++rr) { acc[rr][0] = 0.f; acc[rr][1] = 0.f; }

    for (int tt = 0; tt < TPQ; ++tt) {
        const int j0 = q * (BJ * TPQ) + tt * BJ;

        // ---- phase 1: raw scores into P, track row max ----
        float lmax = -1e30f;
        const float* eb = edges + ((size_t)i * N + (size_t)(j0 + s)) * 5;
        #pragma unroll
        for (int k = 0; k < 16; ++k) {
            const float* e = eb + k * (32 * 5);
            float d = e[0] * ae0;
            d = fmaf(e[1], ae1, d);
            d = fmaf(e[2], ae2, d);
            d = fmaf(e[3], ae3, d);
            d = fmaf(e[4], ae4, d);
            const int j = j0 + s + k * 32;
            float v = si + d + s_jv[j];
            v = v > 0.f ? v : 0.2f * v;   // leaky relu BEFORE mask (matches ref)
            if (j == i) v = NEGV;
            P[q][r1][s + k * 32] = v;
            lmax = fmaxf(lmax, v);
        }
        #pragma unroll
        for (int off = 16; off >= 1; off >>= 1)
            lmax = fmaxf(lmax, __shfl_xor(lmax, off));
        const float newm = fmaxf(m, lmax);
        const float f = __expf(m - newm);
        m = newm;
        // exp in place, accumulate row sum
        float lsum = 0.f;
        #pragma unroll
        for (int k = 0; k < 16; ++k) {
            float p = __expf(P[q][r1][s + k * 32] - m);
            P[q][r1][s + k * 32] = p;
            lsum += p;
        }
        #pragma unroll
        for (int off = 16; off >= 1; off >>= 1)
            lsum += __shfl_xor(lsum, off);
        l = l * f + lsum;
        if (s == 0) fbuf[q][r1] = f;
        __syncthreads();

        // ---- phase 2: PV over this tile's 128-j slice, 2 cols/thread ----
        #pragma unroll
        for (int rr = 0; rr < BI; ++rr) {
            const float fr = fbuf[q][rr];
            acc[rr][0] *= fr;
            acc[rr][1] *= fr;
        }
        const int jb = jq * 128;
        const float* whp = wh + (size_t)(j0 + jb) * OUTD + 2 * c2;
        #pragma unroll 2
        for (int jj = 0; jj < 128; jj += 4) {
            const float2 w0 = *(const float2*)(whp + (size_t)(jj + 0) * OUTD);
            const float2 w1 = *(const float2*)(whp + (size_t)(jj + 1) * OUTD);
            const float2 w2 = *(const float2*)(whp + (size_t)(jj + 2) * OUTD);
            const float2 w3 = *(const float2*)(whp + (size_t)(jj + 3) * OUTD);
            #pragma unroll
            for (int rr = 0; rr < BI; ++rr) {
                const float4 pv = *(const float4*)&P[q][rr][jb + jj];
                acc[rr][0] = fmaf(pv.x, w0.x, acc[rr][0]);
                acc[rr][1] = fmaf(pv.x, w0.y, acc[rr][1]);
                acc[rr][0] = fmaf(pv.y, w1.x, acc[rr][0]);
                acc[rr][1] = fmaf(pv.y, w1.y, acc[rr][1]);
                acc[rr][0] = fmaf(pv.z, w2.x, acc[rr][0]);
                acc[rr][1] = fmaf(pv.z, w2.y, acc[rr][1]);
                acc[rr][0] = fmaf(pv.w, w3.x, acc[rr][0]);
                acc[rr][1] = fmaf(pv.w, w3.y, acc[rr][1]);
            }
        }
        __syncthreads();   // P reusable next tile
    }

    if (s == 0) { mbuf[q][r1] = m; lbuf[q][r1] = l; }
    __syncthreads();

    // ---- cross-quarter merge: scale partials into red (overlays P) ----
    float* red = &P[0][0][0];   // [16][BI][128] = 16384 floats <= 16640
    #pragma unroll
    for (int rr = 0; rr < BI; ++rr) {
        const float M = fmaxf(fmaxf(mbuf[0][rr], mbuf[1][rr]),
                              fmaxf(mbuf[2][rr], mbuf[3][rr]));
        const float sc = __expf(mbuf[q][rr] - M);
        const int base = ((q * 4 + jq) * BI + rr) * 128 + 2 * c2;
        red[base]     = acc[rr][0] * sc;
        red[base + 1] = acc[rr][1] * sc;
    }
    __syncthreads();

    {
        const int ro = t >> 7;       // 0..7
        const int co = t & 127;
        float sum = 0.f;
        #pragma unroll
        for (int k = 0; k < 16; ++k) sum += red[(k * BI + ro) * 128 + co];
        const float M = fmaxf(fmaxf(mbuf[0][ro], mbuf[1][ro]),
                              fmaxf(mbuf[2][ro], mbuf[3][ro]));
        const float L = lbuf[0][ro] * __expf(mbuf[0][ro] - M)
                      + lbuf[1][ro] * __expf(mbuf[1][ro] - M)
                      + lbuf[2][ro] * __expf(mbuf[2][ro] - M)
                      + lbuf[3][ro] * __expf(mbuf[3][ro] - M);
        out[(size_t)(i0 + ro) * OUTD + co] = sum / L;
    }
}

extern "C" void kernel_launch(void* const* d_in, const int* in_sizes, int n_in,
                              void* d_out, int out_size, void* d_ws, size_t ws_size,
                              hipStream_t stream) {
    // inputs: 0=ids(int, unused), 1=lstm_out, 2=edges_list, 3=W, 4=a, 5=first(unused)
    const float* lstm_out = (const float*)d_in[1];
    const float* edges    = (const float*)d_in[2];
    const float* W        = (const float*)d_in[3];
    const float* a        = (const float*)d_in[4];
    float* out = (float*)d_out;

    float* wh  = (float*)d_ws;                 // 4096*128 f32 = 2 MB
    float* s_i = wh + (size_t)N * OUTD;        // 4096 f32
    float* s_j = s_i + N;                      // 4096 f32

    wh_kernel<<<N / 16, 256, 0, stream>>>(lstm_out, W, wh);
    sij_kernel<<<N, 128, 0, stream>>>(wh, a, s_i, s_j);
    gat_fused<<<N / BI, 1024, 0, stream>>>(edges, wh, s_i, s_j, out, a);
}